// Round 13
// baseline (993.666 us; speedup 1.0000x reference)
//
#include <hip/hip_runtime.h>
#include <hip/hip_bf16.h>

#define NUM_E 64
#define KTOP 8
#define CAP 512
#define TT 2048
#define DD 2048
#define HH 1024

#define BK 32
#define LDSK 36  // 72B rows: b64 access classes uniform over banks (9 coprime 16)

typedef __attribute__((ext_vector_type(4))) float f4v;
typedef __attribute__((ext_vector_type(8))) short bf16x8;
typedef __attribute__((ext_vector_type(4))) short bf16x4;

static __device__ __forceinline__ short f2bf(float f) {
    __bf16 b = (__bf16)f;
    return __builtin_bit_cast(short, b);
}
static __device__ __forceinline__ int imin(int a, int b) { return a < b ? a : b; }

// Barrier WITHOUT vmcnt drain: LDS ops committed (lgkmcnt(0)); global loads
// in flight stay in flight across the barrier.
static __device__ __forceinline__ void pipe_barrier() {
    asm volatile("s_waitcnt lgkmcnt(0)" ::: "memory");
    __builtin_amdgcn_s_barrier();
}

// ---------------- init: zero counts ----------------
__global__ __launch_bounds__(64) void k_init(int* __restrict__ counts) {
    counts[threadIdx.x] = 0;
}

// ---------------- prep: x f32 -> bf16 (stored in out[] region, free 8MB) ----
__global__ __launch_bounds__(256) void k_prep(const float* __restrict__ x,
                                              ushort* __restrict__ xbf) {
    int idx = blockIdx.x * 256 + threadIdx.x;
    size_t i8 = (size_t)idx * 8;
    f4v v0 = *(const f4v*)(x + i8);
    f4v v1 = *(const f4v*)(x + i8 + 4);
    bf16x8 o = {f2bf(v0[0]), f2bf(v0[1]), f2bf(v0[2]), f2bf(v0[3]),
                f2bf(v1[0]), f2bf(v1[1]), f2bf(v1[2]), f2bf(v1[3])};
    *(bf16x8*)(xbf + i8) = o;
}

// ---------------- zero out[] (after gateup consumed xbf, before down) -------
__global__ __launch_bounds__(256) void k_zero(float* __restrict__ out) {
    int idx = blockIdx.x * 256 + threadIdx.x;
    f4v z = {0.f, 0.f, 0.f, 0.f};
    ((f4v*)out)[idx] = z;
}

// ---------------- router: logits = x @ gate_w (f32, exact) ----------------
#define RTOK 8
__global__ __launch_bounds__(256) void k_router(const float* __restrict__ x,
                                                const float* __restrict__ gw,
                                                float* __restrict__ logits) {
    __shared__ float xs[RTOK][512];
    const int tid = threadIdx.x;
    const int lane = tid & 63, wid = tid >> 6;
    const int t0 = blockIdx.x * RTOK;
    float a0 = 0.f, a1 = 0.f;
    for (int c = 0; c < DD / 512; ++c) {
        __syncthreads();
#pragma unroll
        for (int u = tid * 4; u < RTOK * 512; u += 1024) {
            int r = u >> 9, col = u & 511;
            *(f4v*)&xs[r][col] = *(const f4v*)&x[(size_t)(t0 + r) * DD + c * 512 + col];
        }
        __syncthreads();
        const float* gcol = gw + (size_t)c * 512 * NUM_E + lane;
#pragma unroll 8
        for (int d = 0; d < 512; ++d) {
            float g = gcol[(size_t)d * NUM_E];
            a0 = fmaf(xs[wid * 2 + 0][d], g, a0);
            a1 = fmaf(xs[wid * 2 + 1][d], g, a1);
        }
    }
    logits[(size_t)(t0 + wid * 2 + 0) * NUM_E + lane] = a0;
    logits[(size_t)(t0 + wid * 2 + 1) * NUM_E + lane] = a1;
}

// ---------------- topk + dispatch ----------------
__global__ __launch_bounds__(256) void k_topk(const float* __restrict__ logits,
                                              int* __restrict__ counts,
                                              int* __restrict__ slot_token,
                                              float* __restrict__ slot_wt) {
    int lane = threadIdx.x & 63, wid = threadIdx.x >> 6;
    int t = blockIdx.x * 4 + wid;
    float l = logits[(size_t)t * NUM_E + lane];
    float m = l;
#pragma unroll
    for (int off = 32; off; off >>= 1) m = fmaxf(m, __shfl_xor(m, off));
    float ex = __expf(l - m);
    float s = ex;
#pragma unroll
    for (int off = 32; off; off >>= 1) s += __shfl_xor(s, off);
    float p = ex / s;
#pragma unroll
    for (int k = 0; k < KTOP; ++k) {
        float v = p;
        int i = lane;
#pragma unroll
        for (int off = 32; off; off >>= 1) {
            float v2 = __shfl_xor(v, off);
            int i2 = __shfl_xor(i, off);
            if (v2 > v || (v2 == v && i2 < i)) { v = v2; i = i2; }
        }
        if (lane == i) {
            int pos = atomicAdd(&counts[i], 1);
            if (pos < CAP) {
                int slot = i * CAP + pos;
                slot_token[slot] = t;
                slot_wt[slot] = v;
            }
            p = -1.0f;
        }
    }
}

// ================= gate+up fused GEMM + SwiGLU -> h =================
// 128x64 tile, 4 waves 2x2, wave 64x32 dual g+u acc.
// A-fragments loaded DIRECTLY from global (no A-LDS): per-lane gather of
// 16B k-octets, double-banked + prefetched a full step ahead. B staged via
// LDS (r8 layout, LDSK=36). k-octet layout {8*g4..8*g4+7} applied to BOTH
// operands (consistent permutation => exact dot). One lgkm barrier/step.
__global__ __launch_bounds__(256, 3) void k_gateup(
    const ushort* __restrict__ xbf, const float* __restrict__ wg, const float* __restrict__ wu,
    const int* __restrict__ counts, const int* __restrict__ slot_token,
    const float* __restrict__ slot_wt, ushort* __restrict__ hbuf) {
    const int e = blockIdx.z;
    int count = counts[e];
    if (count > CAP) count = CAP;
    const int mrow0 = blockIdx.y * 128;
    if (mrow0 >= count) return;
    const int ncol0 = blockIdx.x * 64;
    const int tid = threadIdx.x;
    const int lane = tid & 63, wid = tid >> 6;
    const int wm = wid >> 1, wn = wid & 1;
    const int lrow = lane & 15, g4 = lane >> 4;

    __shared__ ushort Bg0[64 * LDSK], Bg1[64 * LDSK];
    __shared__ ushort Bu0[64 * LDSK], Bu1[64 * LDSK];

    // A-frag direct pointers: lane (lrow,g4) reads row wm*64+m*16+lrow,
    // k-octet g4 (16B). 4 lanes/row -> 64B/row per instruction.
    const ushort* aptrF[4];
#pragma unroll
    for (int m = 0; m < 4; ++m) {
        int row = wm * 64 + m * 16 + lrow;
        int rg = imin(mrow0 + row, count - 1);
        int tok = slot_token[e * CAP + rg];
        aptrF[m] = xbf + (size_t)tok * DD + g4 * 8;
    }

    // B staging (r8 exact): tid&128 selects wg/wu; 4 h-cols x 4 k per unit.
    const int bidx = tid & 127;
    const int bc0 = (bidx & 15) * 4;
    const int bk0 = (bidx >> 4) * 4;
    const float* bptr = ((tid & 128) ? wu : wg) + ((size_t)e * DD + bk0) * HH + ncol0 + bc0;
    ushort* bl0 = (tid & 128) ? Bu0 : Bg0;
    ushort* bl1 = (tid & 128) ? Bu1 : Bg1;

    f4v stB[4];
    bf16x8 afA[4], afB[4];   // double-banked A fragments
    f4v accg[4][2], accu[4][2];
    const f4v fz = {0.f, 0.f, 0.f, 0.f};
#pragma unroll
    for (int m = 0; m < 4; ++m)
#pragma unroll
        for (int n = 0; n < 2; ++n) { accg[m][n] = fz; accu[m][n] = fz; }

#define GU_AF(AF, KO) { \
    _Pragma("unroll") for (int m_ = 0; m_ < 4; ++m_) \
        AF[m_] = *(const bf16x8*)(aptrF[m_] + (KO)); }

#define GU_BLOAD(KO) { \
    _Pragma("unroll") for (int j_ = 0; j_ < 4; ++j_) \
        stB[j_] = *(const f4v*)(bptr + ((size_t)(KO) + j_) * HH); }

#define GU_BWRITE(BLB) { \
    _Pragma("unroll") for (int i_ = 0; i_ < 4; ++i_) { \
        bf16x4 col_ = {f2bf(stB[0][i_]), f2bf(stB[1][i_]), f2bf(stB[2][i_]), f2bf(stB[3][i_])}; \
        *(bf16x4*)&BLB[(bc0 + i_) * LDSK + bk0] = col_; } }

// B-frag: k-octet g4 (elems c..c+7, two b64s) matching A's direct octet.
#define GU_FM(AF, BG, BU) { \
    _Pragma("unroll") for (int n_ = 0; n_ < 2; ++n_) { \
        const int c_ = (wn * 32 + n_ * 16 + lrow) * LDSK + g4 * 8; \
        union { bf16x8 v8; bf16x4 v4[2]; } ug_, uu_; \
        ug_.v4[0] = *(const bf16x4*)&BG[c_]; ug_.v4[1] = *(const bf16x4*)&BG[c_ + 4]; \
        uu_.v4[0] = *(const bf16x4*)&BU[c_]; uu_.v4[1] = *(const bf16x4*)&BU[c_ + 4]; \
        _Pragma("unroll") for (int m_ = 0; m_ < 4; ++m_) { \
            accg[m_][n_] = __builtin_amdgcn_mfma_f32_16x16x32_bf16(AF[m_], ug_.v8, accg[m_][n_], 0, 0, 0); \
            accu[m_][n_] = __builtin_amdgcn_mfma_f32_16x16x32_bf16(AF[m_], uu_.v8, accu[m_][n_], 0, 0, 0); } } }

    // prologue: B(t0) load+write; A(t0),A(t1) frag loads; B(t1) load in flight
    GU_BLOAD(0);
    GU_AF(afA, 0);
    GU_BWRITE(bl0);          // waits stB(t0); A loads newer, stay in flight
    GU_BLOAD(BK);
    GU_AF(afB, BK);
    pipe_barrier();

    const int NK = DD / BK;  // 64, even
    for (int kt = 0; kt < NK; kt += 2) {
        const int ko2 = imin(kt + 2, NK - 1) * BK;  // clamped tail: dummy loads,
        const int ko3 = imin(kt + 3, NK - 1) * BK;  // never consumed
        // phase 0: consume tile kt (buf0, afA)
        GU_BWRITE(bl1);      // stB = t(kt+1), loads a full phase old
        GU_BLOAD(ko2);       // stB <- B(kt+2)
        GU_FM(afA, Bg0, Bu0);
        GU_AF(afA, ko2);     // A(kt+2): full-phase cover
        pipe_barrier();
        // phase 1: consume tile kt+1 (buf1, afB)
        GU_BWRITE(bl0);      // stB = t(kt+2)
        GU_BLOAD(ko3);       // stB <- B(kt+3)
        GU_FM(afB, Bg1, Bu1);
        GU_AF(afB, ko3);     // A(kt+3)
        pipe_barrier();
    }

    // epilogue: h = silu(g)*u * gate-weight, bf16
#pragma unroll
    for (int m = 0; m < 4; ++m) {
#pragma unroll
        for (int r = 0; r < 4; ++r) {
            int row = mrow0 + wm * 64 + m * 16 + g4 * 4 + r;
            if (row < count) {
                float wgt = slot_wt[e * CAP + row];
                size_t base = (size_t)(e * CAP + row) * HH + ncol0 + wn * 32;
#pragma unroll
                for (int n = 0; n < 2; ++n) {
                    float g = accg[m][n][r], uv = accu[m][n][r];
                    float hv = (g / (1.f + __expf(-g))) * uv * wgt;
                    hbuf[base + n * 16 + lrow] = (ushort)f2bf(hv);
                }
            }
        }
    }
}

// ================= down GEMM + scatter-add into out =================
// 128x128 tile, 4 waves 2x2, wave 64x64. Same A-direct + B-LDS pipeline.
__global__ __launch_bounds__(256, 3) void k_down(
    const ushort* __restrict__ hbuf, const float* __restrict__ wd,
    const int* __restrict__ counts, const int* __restrict__ slot_token,
    float* __restrict__ out) {
    const int e = blockIdx.z;
    int count = counts[e];
    if (count > CAP) count = CAP;
    const int mrow0 = blockIdx.y * 128;
    if (mrow0 >= count) return;
    const int ncol0 = blockIdx.x * 128;
    const int tid = threadIdx.x;
    const int lane = tid & 63, wid = tid >> 6;
    const int wm = wid >> 1, wn = wid & 1;
    const int lrow = lane & 15, g4 = lane >> 4;

    __shared__ ushort Bs0[128 * LDSK], Bs1[128 * LDSK];

    const ushort* aptrF[4];
#pragma unroll
    for (int m = 0; m < 4; ++m) {
        int row = wm * 64 + m * 16 + lrow;
        int rg = imin(mrow0 + row, count - 1);
        aptrF[m] = hbuf + (size_t)(e * CAP + rg) * HH + g4 * 8;
    }
    const int bc0 = (tid & 31) * 4;
    const int bk0 = ((tid >> 5) & 7) * 4;
    const float* bptr = wd + ((size_t)e * HH + bk0) * DD + ncol0 + bc0;

    f4v stB[4];
    bf16x8 afA[4], afB[4];
    f4v acc[4][4];
    const f4v fz = {0.f, 0.f, 0.f, 0.f};
#pragma unroll
    for (int m = 0; m < 4; ++m)
#pragma unroll
        for (int n = 0; n < 4; ++n) acc[m][n] = fz;

#define DN_AF(AF, KO) { \
    _Pragma("unroll") for (int m_ = 0; m_ < 4; ++m_) \
        AF[m_] = *(const bf16x8*)(aptrF[m_] + (KO)); }

#define DN_BLOAD(KO) { \
    _Pragma("unroll") for (int j_ = 0; j_ < 4; ++j_) \
        stB[j_] = *(const f4v*)(bptr + ((size_t)(KO) + j_) * DD); }

#define DN_BWRITE(BSB) { \
    _Pragma("unroll") for (int i_ = 0; i_ < 4; ++i_) { \
        bf16x4 col_ = {f2bf(stB[0][i_]), f2bf(stB[1][i_]), f2bf(stB[2][i_]), f2bf(stB[3][i_])}; \
        *(bf16x4*)&BSB[(bc0 + i_) * LDSK + bk0] = col_; } }

#define DN_FM(AF, BS) { \
    _Pragma("unroll") for (int n_ = 0; n_ < 4; ++n_) { \
        const int c_ = (wn * 64 + n_ * 16 + lrow) * LDSK + g4 * 8; \
        union { bf16x8 v8; bf16x4 v4[2]; } ub_; \
        ub_.v4[0] = *(const bf16x4*)&BS[c_]; ub_.v4[1] = *(const bf16x4*)&BS[c_ + 4]; \
        _Pragma("unroll") for (int m_ = 0; m_ < 4; ++m_) \
            acc[m_][n_] = __builtin_amdgcn_mfma_f32_16x16x32_bf16(AF[m_], ub_.v8, acc[m_][n_], 0, 0, 0); } }

    DN_BLOAD(0);
    DN_AF(afA, 0);
    DN_BWRITE(Bs0);
    DN_BLOAD(BK);
    DN_AF(afB, BK);
    pipe_barrier();

    const int NK = HH / BK;  // 32, even
    for (int kt = 0; kt < NK; kt += 2) {
        const int ko2 = imin(kt + 2, NK - 1) * BK;
        const int ko3 = imin(kt + 3, NK - 1) * BK;
        DN_BWRITE(Bs1);
        DN_BLOAD(ko2);
        DN_FM(afA, Bs0);
        DN_AF(afA, ko2);
        pipe_barrier();
        DN_BWRITE(Bs0);
        DN_BLOAD(ko3);
        DN_FM(afB, Bs1);
        DN_AF(afB, ko3);
        pipe_barrier();
    }

#pragma unroll
    for (int m = 0; m < 4; ++m) {
#pragma unroll
        for (int r = 0; r < 4; ++r) {
            int row = mrow0 + wm * 64 + m * 16 + g4 * 4 + r;
            if (row < count) {
                int tok = slot_token[e * CAP + row];
                float* obase = out + (size_t)tok * DD + ncol0 + wn * 64;
#pragma unroll
                for (int n = 0; n < 4; ++n) atomicAdd(obase + n * 16 + lrow, acc[m][n][r]);
            }
        }
    }
}

extern "C" void kernel_launch(void* const* d_in, const int* in_sizes, int n_in,
                              void* d_out, int out_size, void* d_ws, size_t ws_size,
                              hipStream_t stream) {
    const float* x = (const float*)d_in[0];       // [1,2048,2048]
    const float* gw = (const float*)d_in[1];      // [2048,64]
    const float* wg = (const float*)d_in[2];      // [64,2048,1024]
    const float* wu = (const float*)d_in[3];      // [64,2048,1024]
    const float* wd = (const float*)d_in[4];      // [64,1024,2048]
    float* out = (float*)d_out;                   // [T*D] then logits [T*E]
    float* logits = out + (size_t)TT * DD;

    char* ws = (char*)d_ws;
    int* counts = (int*)ws;                                      // 256 B
    int* slot_token = (int*)(ws + 1024);                         // 128 KB
    float* slot_wt = (float*)(ws + 1024 + NUM_E * CAP * 4);      // 128 KB
    ushort* hbuf = (ushort*)(ws + 1024 + 2 * NUM_E * CAP * 4);   // 64 MB bf16 [E*CAP][H]
    // xbf (8 MB bf16 copy of x) lives in out[]: written by k_prep, read by
    // k_gateup, erased by k_zero before k_down's atomics.
    ushort* xbf = (ushort*)out;

    k_init<<<1, 64, 0, stream>>>(counts);
    k_prep<<<(TT * DD / 8) / 256, 256, 0, stream>>>(x, xbf);
    k_router<<<TT / RTOK, 256, 0, stream>>>(x, gw, logits);
    k_topk<<<TT / 4, 256, 0, stream>>>(logits, counts, slot_token, slot_wt);
    k_gateup<<<dim3(HH / 64, CAP / 128, NUM_E), 256, 0, stream>>>(xbf, wg, wu, counts, slot_token, slot_wt, hbuf);
    k_zero<<<(TT * DD / 4) / 256, 256, 0, stream>>>(out);
    k_down<<<dim3(DD / 128, CAP / 128, NUM_E), 256, 0, stream>>>(hbuf, wd, counts, slot_token, out);
}

// Round 14
// 850.031 us; speedup vs baseline: 1.1690x; 1.1690x over previous
//
#include <hip/hip_runtime.h>
#include <hip/hip_bf16.h>

#define NUM_E 64
#define KTOP 8
#define CAP 512
#define TT 2048
#define DD 2048
#define HH 1024

#define BKT 64   // K-tile: one barrier + one counted vmcnt per 64-k

typedef __attribute__((ext_vector_type(4))) float f4v;
typedef __attribute__((ext_vector_type(8))) short bf16x8;
typedef __attribute__((ext_vector_type(4))) short bf16x4;

static __device__ __forceinline__ short f2bf(float f) {
    __bf16 b = (__bf16)f;
    return __builtin_bit_cast(short, b);
}
static __device__ __forceinline__ int imin(int a, int b) { return a < b ? a : b; }

// direct global->LDS DMA, 16B per lane; dest = wave-uniform base + lane*16
static __device__ __forceinline__ void load_lds16(const ushort* g, ushort* l) {
    __builtin_amdgcn_global_load_lds(
        (const __attribute__((address_space(1))) unsigned int*)g,
        (__attribute__((address_space(3))) unsigned int*)l, 16, 0, 0);
}

// lgkm-only barrier: LDS ops committed; global loads stay in flight (T4).
static __device__ __forceinline__ void pipe_barrier() {
    asm volatile("s_waitcnt lgkmcnt(0)" ::: "memory");
    __builtin_amdgcn_s_barrier();
}

// ---------------- init: zero counts ----------------
__global__ __launch_bounds__(64) void k_init(int* __restrict__ counts) {
    counts[threadIdx.x] = 0;
}

// ---------------- prep: x f32 -> bf16 (stored in out[] region, free 8MB) ----
__global__ __launch_bounds__(256) void k_prep(const float* __restrict__ x,
                                              ushort* __restrict__ xbf) {
    int idx = blockIdx.x * 256 + threadIdx.x;
    size_t i8 = (size_t)idx * 8;
    f4v v0 = *(const f4v*)(x + i8);
    f4v v1 = *(const f4v*)(x + i8 + 4);
    bf16x8 o = {f2bf(v0[0]), f2bf(v0[1]), f2bf(v0[2]), f2bf(v0[3]),
                f2bf(v1[0]), f2bf(v1[1]), f2bf(v1[2]), f2bf(v1[3])};
    *(bf16x8*)(xbf + i8) = o;
}

// ---------------- zero out[] (after gateup consumed xbf, before down) -------
__global__ __launch_bounds__(256) void k_zero(float* __restrict__ out) {
    int idx = blockIdx.x * 256 + threadIdx.x;
    f4v z = {0.f, 0.f, 0.f, 0.f};
    ((f4v*)out)[idx] = z;
}

// ---------------- router: logits = x @ gate_w (f32, exact) ----------------
#define RTOK 8
__global__ __launch_bounds__(256) void k_router(const float* __restrict__ x,
                                                const float* __restrict__ gw,
                                                float* __restrict__ logits) {
    __shared__ float xs[RTOK][512];
    const int tid = threadIdx.x;
    const int lane = tid & 63, wid = tid >> 6;
    const int t0 = blockIdx.x * RTOK;
    float a0 = 0.f, a1 = 0.f;
    for (int c = 0; c < DD / 512; ++c) {
        __syncthreads();
#pragma unroll
        for (int u = tid * 4; u < RTOK * 512; u += 1024) {
            int r = u >> 9, col = u & 511;
            *(f4v*)&xs[r][col] = *(const f4v*)&x[(size_t)(t0 + r) * DD + c * 512 + col];
        }
        __syncthreads();
        const float* gcol = gw + (size_t)c * 512 * NUM_E + lane;
#pragma unroll 8
        for (int d = 0; d < 512; ++d) {
            float g = gcol[(size_t)d * NUM_E];
            a0 = fmaf(xs[wid * 2 + 0][d], g, a0);
            a1 = fmaf(xs[wid * 2 + 1][d], g, a1);
        }
    }
    logits[(size_t)(t0 + wid * 2 + 0) * NUM_E + lane] = a0;
    logits[(size_t)(t0 + wid * 2 + 1) * NUM_E + lane] = a1;
}

// ---------------- topk + dispatch ----------------
__global__ __launch_bounds__(256) void k_topk(const float* __restrict__ logits,
                                              int* __restrict__ counts,
                                              int* __restrict__ slot_token,
                                              float* __restrict__ slot_wt) {
    int lane = threadIdx.x & 63, wid = threadIdx.x >> 6;
    int t = blockIdx.x * 4 + wid;
    float l = logits[(size_t)t * NUM_E + lane];
    float m = l;
#pragma unroll
    for (int off = 32; off; off >>= 1) m = fmaxf(m, __shfl_xor(m, off));
    float ex = __expf(l - m);
    float s = ex;
#pragma unroll
    for (int off = 32; off; off >>= 1) s += __shfl_xor(s, off);
    float p = ex / s;
#pragma unroll
    for (int k = 0; k < KTOP; ++k) {
        float v = p;
        int i = lane;
#pragma unroll
        for (int off = 32; off; off >>= 1) {
            float v2 = __shfl_xor(v, off);
            int i2 = __shfl_xor(i, off);
            if (v2 > v || (v2 == v && i2 < i)) { v = v2; i = i2; }
        }
        if (lane == i) {
            int pos = atomicAdd(&counts[i], 1);
            if (pos < CAP) {
                int slot = i * CAP + pos;
                slot_token[slot] = t;
                slot_wt[slot] = v;
            }
            p = -1.0f;
        }
    }
}

// ================= gate+up fused GEMM + SwiGLU -> h =================
// BM=128, BN=64, BK=64. 4 waves 2x2; wave 64x32 dual g+u acc.
// A: global_load_lds DMA into linear [128][64] with source-octet XOR; reads
//    are single b128 (octet (kh*4+g4)^(row&7)).
// B: [col][64] 128B rows, T2 XOR swizzle (idx ^= (col&7)<<3): 4 b128 writes
//    per thread per tile, single-b128 frag reads. All classes uniform-8/granule.
// One lgkm barrier + one explicit vmcnt(8) per tile (drains own A-DMA; the 8
// B(t+2) loads stay in flight across the barrier).
__global__ __launch_bounds__(256, 2) void k_gateup(
    const ushort* __restrict__ xbf, const float* __restrict__ wg, const float* __restrict__ wu,
    const int* __restrict__ counts, const int* __restrict__ slot_token,
    const float* __restrict__ slot_wt, ushort* __restrict__ hbuf) {
    const int e = blockIdx.z;
    int count = counts[e];
    if (count > CAP) count = CAP;
    const int mrow0 = blockIdx.y * 128;
    if (mrow0 >= count) return;
    const int ncol0 = blockIdx.x * 64;
    const int tid = threadIdx.x;
    const int lane = tid & 63, wid = tid >> 6;
    const int wm = wid >> 1, wn = wid & 1;
    const int lrow = lane & 15, g4 = lane >> 4;

    __shared__ ushort As0[128 * 64], As1[128 * 64];      // 16KB each
    __shared__ ushort Bg0[64 * 64], Bg1[64 * 64];        // 8KB each
    __shared__ ushort Bu0[64 * 64], Bu1[64 * 64];

    // A DMA: wave stages rows [wid*32, wid*32+32); instr i: rows i*8+(l>>3),
    // LDS slot l&7 (linear), source octet (l&7)^(l>>3)  [row&7 = l>>3].
    const ushort* aglb[4];
#pragma unroll
    for (int i = 0; i < 4; ++i) {
        int rl = wid * 32 + i * 8 + (lane >> 3);
        int rg = imin(mrow0 + rl, count - 1);
        int tok = slot_token[e * CAP + rg];
        aglb[i] = xbf + (size_t)tok * DD + (((lane & 7) ^ (lane >> 3)) * 8);
    }
    // B staging: tid&128 selects wg/wu. bidx=tid&127: cols bc0..bc0+3
    // (bc0=(bidx&15)*4), k-octet ko8=(bidx>>4)*8.
    const int bidx = tid & 127;
    const int bc0 = (bidx & 15) * 4;
    const int ko8 = (bidx >> 4) * 8;
    const float* bptr = ((tid & 128) ? wu : wg) + ((size_t)e * DD + ko8) * HH + ncol0 + bc0;
    ushort* bl0 = (tid & 128) ? Bu0 : Bg0;
    ushort* bl1 = (tid & 128) ? Bu1 : Bg1;

    f4v stB[8];
    f4v accg[4][2], accu[4][2];
    const f4v fz = {0.f, 0.f, 0.f, 0.f};
#pragma unroll
    for (int m = 0; m < 4; ++m)
#pragma unroll
        for (int n = 0; n < 2; ++n) { accg[m][n] = fz; accu[m][n] = fz; }

#define GU_ADMA(ASB, KO) { \
    load_lds16(aglb[0] + (KO), &ASB[(wid * 32 + 0) * 64]); \
    load_lds16(aglb[1] + (KO), &ASB[(wid * 32 + 8) * 64]); \
    load_lds16(aglb[2] + (KO), &ASB[(wid * 32 + 16) * 64]); \
    load_lds16(aglb[3] + (KO), &ASB[(wid * 32 + 24) * 64]); }

#define GU_BLOAD(KO) { \
    _Pragma("unroll") for (int j_ = 0; j_ < 8; ++j_) \
        stB[j_] = *(const f4v*)(bptr + (size_t)((KO) + j_) * HH); }

#define GU_BWRITE(BLB) { \
    _Pragma("unroll") for (int i_ = 0; i_ < 4; ++i_) { \
        const int col_ = bc0 + i_; \
        bf16x8 v_ = {f2bf(stB[0][i_]), f2bf(stB[1][i_]), f2bf(stB[2][i_]), f2bf(stB[3][i_]), \
                     f2bf(stB[4][i_]), f2bf(stB[5][i_]), f2bf(stB[6][i_]), f2bf(stB[7][i_])}; \
        *(bf16x8*)&BLB[(col_ * 64 + ko8) ^ ((col_ & 7) << 3)] = v_; } }

#define GU_FM(AS, BG, BU) { \
    _Pragma("unroll") for (int kh_ = 0; kh_ < 2; ++kh_) { \
        bf16x8 af_[4]; \
        _Pragma("unroll") for (int m_ = 0; m_ < 4; ++m_) { \
            const int row_ = wm * 64 + m_ * 16 + lrow; \
            af_[m_] = *(const bf16x8*)&AS[row_ * 64 + (((kh_ * 4 + g4) ^ (row_ & 7)) * 8)]; } \
        _Pragma("unroll") for (int n_ = 0; n_ < 2; ++n_) { \
            const int col_ = wn * 32 + n_ * 16 + lrow; \
            const int bi_ = (col_ * 64 + (kh_ * 4 + g4) * 8) ^ ((col_ & 7) << 3); \
            bf16x8 bg_ = *(const bf16x8*)&BG[bi_]; \
            bf16x8 bu_ = *(const bf16x8*)&BU[bi_]; \
            _Pragma("unroll") for (int m_ = 0; m_ < 4; ++m_) { \
                accg[m_][n_] = __builtin_amdgcn_mfma_f32_16x16x32_bf16(af_[m_], bg_, accg[m_][n_], 0, 0, 0); \
                accu[m_][n_] = __builtin_amdgcn_mfma_f32_16x16x32_bf16(af_[m_], bu_, accu[m_][n_], 0, 0, 0); } } } }

#define GU_TILE(AC, BGC, BUC, AO, BLO, KO1, KO2) { \
    GU_ADMA(AO, KO1); \
    __builtin_amdgcn_sched_barrier(0); \
    GU_BWRITE(BLO); \
    GU_BLOAD(KO2); \
    __builtin_amdgcn_sched_barrier(0); \
    GU_FM(AC, BGC, BUC); \
    asm volatile("s_waitcnt vmcnt(8)" ::: "memory"); \
    __builtin_amdgcn_sched_barrier(0); \
    pipe_barrier(); }

    // prologue: A(t0) DMA; B(t0) load+write; B(t1) load; vmcnt(8) drains A-DMA
    GU_ADMA(As0, 0);
    __builtin_amdgcn_sched_barrier(0);
    GU_BLOAD(0);
    GU_BWRITE(bl0);
    GU_BLOAD(BKT);
    asm volatile("s_waitcnt vmcnt(8)" ::: "memory");
    __builtin_amdgcn_sched_barrier(0);
    pipe_barrier();

    const int NKT = DD / BKT;  // 32, even
    for (int kt = 0; kt < NKT; kt += 2) {
        const int k1 = imin(kt + 1, NKT - 1) * BKT;   // clamped tail: dummy work,
        const int k2 = imin(kt + 2, NKT - 1) * BKT;   // never consumed
        const int k3 = imin(kt + 3, NKT - 1) * BKT;
        GU_TILE(As0, Bg0, Bu0, As1, bl1, k1, k2);     // consume tile kt
        GU_TILE(As1, Bg1, Bu1, As0, bl0, k2, k3);     // consume tile kt+1
    }

    // epilogue: h = silu(g)*u * gate-weight, bf16
#pragma unroll
    for (int m = 0; m < 4; ++m) {
#pragma unroll
        for (int r = 0; r < 4; ++r) {
            int row = mrow0 + wm * 64 + m * 16 + g4 * 4 + r;
            if (row < count) {
                float wgt = slot_wt[e * CAP + row];
                size_t base = (size_t)(e * CAP + row) * HH + ncol0 + wn * 32;
#pragma unroll
                for (int n = 0; n < 2; ++n) {
                    float g = accg[m][n][r], uv = accu[m][n][r];
                    float hv = (g / (1.f + __expf(-g))) * uv * wgt;
                    hbuf[base + n * 16 + lrow] = (ushort)f2bf(hv);
                }
            }
        }
    }
}

// ================= down GEMM + scatter-add into out =================
// BM=128, BN=128, BK=64. Same DMA-A + swizzled-B template; wave 64x64.
__global__ __launch_bounds__(256, 2) void k_down(
    const ushort* __restrict__ hbuf, const float* __restrict__ wd,
    const int* __restrict__ counts, const int* __restrict__ slot_token,
    float* __restrict__ out) {
    const int e = blockIdx.z;
    int count = counts[e];
    if (count > CAP) count = CAP;
    const int mrow0 = blockIdx.y * 128;
    if (mrow0 >= count) return;
    const int ncol0 = blockIdx.x * 128;
    const int tid = threadIdx.x;
    const int lane = tid & 63, wid = tid >> 6;
    const int wm = wid >> 1, wn = wid & 1;
    const int lrow = lane & 15, g4 = lane >> 4;

    __shared__ ushort As0[128 * 64], As1[128 * 64];      // 16KB each
    __shared__ ushort Bs0[128 * 64], Bs1[128 * 64];      // 16KB each

    const ushort* aglb[4];
#pragma unroll
    for (int i = 0; i < 4; ++i) {
        int rl = wid * 32 + i * 8 + (lane >> 3);
        int rg = imin(mrow0 + rl, count - 1);
        aglb[i] = hbuf + (size_t)(e * CAP + rg) * HH + (((lane & 7) ^ (lane >> 3)) * 8);
    }
    // B: 256 threads; cols bc0..+3 (bc0=(tid&31)*4), k-octet ko8=((tid>>5)&7)*8
    const int bc0 = (tid & 31) * 4;
    const int ko8 = ((tid >> 5) & 7) * 8;
    const float* bptr = wd + ((size_t)e * HH + ko8) * DD + ncol0 + bc0;

    f4v stB[8];
    f4v acc[4][4];
    const f4v fz = {0.f, 0.f, 0.f, 0.f};
#pragma unroll
    for (int m = 0; m < 4; ++m)
#pragma unroll
        for (int n = 0; n < 4; ++n) acc[m][n] = fz;

#define DN_ADMA(ASB, KO) { \
    load_lds16(aglb[0] + (KO), &ASB[(wid * 32 + 0) * 64]); \
    load_lds16(aglb[1] + (KO), &ASB[(wid * 32 + 8) * 64]); \
    load_lds16(aglb[2] + (KO), &ASB[(wid * 32 + 16) * 64]); \
    load_lds16(aglb[3] + (KO), &ASB[(wid * 32 + 24) * 64]); }

#define DN_BLOAD(KO) { \
    _Pragma("unroll") for (int j_ = 0; j_ < 8; ++j_) \
        stB[j_] = *(const f4v*)(bptr + (size_t)((KO) + j_) * DD); }

#define DN_BWRITE(BSB) { \
    _Pragma("unroll") for (int i_ = 0; i_ < 4; ++i_) { \
        const int col_ = bc0 + i_; \
        bf16x8 v_ = {f2bf(stB[0][i_]), f2bf(stB[1][i_]), f2bf(stB[2][i_]), f2bf(stB[3][i_]), \
                     f2bf(stB[4][i_]), f2bf(stB[5][i_]), f2bf(stB[6][i_]), f2bf(stB[7][i_])}; \
        *(bf16x8*)&BSB[(col_ * 64 + ko8) ^ ((col_ & 7) << 3)] = v_; } }

#define DN_FM(AS, BS) { \
    _Pragma("unroll") for (int kh_ = 0; kh_ < 2; ++kh_) { \
        bf16x8 af_[4]; \
        _Pragma("unroll") for (int m_ = 0; m_ < 4; ++m_) { \
            const int row_ = wm * 64 + m_ * 16 + lrow; \
            af_[m_] = *(const bf16x8*)&AS[row_ * 64 + (((kh_ * 4 + g4) ^ (row_ & 7)) * 8)]; } \
        _Pragma("unroll") for (int n_ = 0; n_ < 4; ++n_) { \
            const int col_ = wn * 64 + n_ * 16 + lrow; \
            const int bi_ = (col_ * 64 + (kh_ * 4 + g4) * 8) ^ ((col_ & 7) << 3); \
            bf16x8 bf_ = *(const bf16x8*)&BS[bi_]; \
            _Pragma("unroll") for (int m_ = 0; m_ < 4; ++m_) \
                acc[m_][n_] = __builtin_amdgcn_mfma_f32_16x16x32_bf16(af_[m_], bf_, acc[m_][n_], 0, 0, 0); } } }

#define DN_TILE(AC, BC, AO, BO, KO1, KO2) { \
    DN_ADMA(AO, KO1); \
    __builtin_amdgcn_sched_barrier(0); \
    DN_BWRITE(BO); \
    DN_BLOAD(KO2); \
    __builtin_amdgcn_sched_barrier(0); \
    DN_FM(AC, BC); \
    asm volatile("s_waitcnt vmcnt(8)" ::: "memory"); \
    __builtin_amdgcn_sched_barrier(0); \
    pipe_barrier(); }

    DN_ADMA(As0, 0);
    __builtin_amdgcn_sched_barrier(0);
    DN_BLOAD(0);
    DN_BWRITE(Bs0);
    DN_BLOAD(BKT);
    asm volatile("s_waitcnt vmcnt(8)" ::: "memory");
    __builtin_amdgcn_sched_barrier(0);
    pipe_barrier();

    const int NKT = HH / BKT;  // 16, even
    for (int kt = 0; kt < NKT; kt += 2) {
        const int k1 = imin(kt + 1, NKT - 1) * BKT;
        const int k2 = imin(kt + 2, NKT - 1) * BKT;
        const int k3 = imin(kt + 3, NKT - 1) * BKT;
        DN_TILE(As0, Bs0, As1, Bs1, k1, k2);
        DN_TILE(As1, Bs1, As0, Bs0, k2, k3);
    }

#pragma unroll
    for (int m = 0; m < 4; ++m) {
#pragma unroll
        for (int r = 0; r < 4; ++r) {
            int row = mrow0 + wm * 64 + m * 16 + g4 * 4 + r;
            if (row < count) {
                int tok = slot_token[e * CAP + row];
                float* obase = out + (size_t)tok * DD + ncol0 + wn * 64;
#pragma unroll
                for (int n = 0; n < 4; ++n) atomicAdd(obase + n * 16 + lrow, acc[m][n][r]);
            }
        }
    }
}

extern "C" void kernel_launch(void* const* d_in, const int* in_sizes, int n_in,
                              void* d_out, int out_size, void* d_ws, size_t ws_size,
                              hipStream_t stream) {
    const float* x = (const float*)d_in[0];       // [1,2048,2048]
    const float* gw = (const float*)d_in[1];      // [2048,64]
    const float* wg = (const float*)d_in[2];      // [64,2048,1024]
    const float* wu = (const float*)d_in[3];      // [64,2048,1024]
    const float* wd = (const float*)d_in[4];      // [64,1024,2048]
    float* out = (float*)d_out;                   // [T*D] then logits [T*E]
    float* logits = out + (size_t)TT * DD;

    char* ws = (char*)d_ws;
    int* counts = (int*)ws;                                      // 256 B
    int* slot_token = (int*)(ws + 1024);                         // 128 KB
    float* slot_wt = (float*)(ws + 1024 + NUM_E * CAP * 4);      // 128 KB
    ushort* hbuf = (ushort*)(ws + 1024 + 2 * NUM_E * CAP * 4);   // 64 MB bf16 [E*CAP][H]
    // xbf (8 MB bf16 copy of x) lives in out[]: written by k_prep, read by
    // k_gateup, erased by k_zero before k_down's atomics.
    ushort* xbf = (ushort*)out;

    k_init<<<1, 64, 0, stream>>>(counts);
    k_prep<<<(TT * DD / 8) / 256, 256, 0, stream>>>(x, xbf);
    k_router<<<TT / RTOK, 256, 0, stream>>>(x, gw, logits);
    k_topk<<<TT / 4, 256, 0, stream>>>(logits, counts, slot_token, slot_wt);
    k_gateup<<<dim3(HH / 64, CAP / 128, NUM_E), 256, 0, stream>>>(xbf, wg, wu, counts, slot_token, slot_wt, hbuf);
    k_zero<<<(TT * DD / 4) / 256, 256, 0, stream>>>(out);
    k_down<<<dim3(DD / 128, CAP / 128, NUM_E), 256, 0, stream>>>(hbuf, wd, counts, slot_token, out);
}